// Round 9
// baseline (1858.830 us; speedup 1.0000x reference)
//
#include <hip/hip_runtime.h>
#include <hip/hip_bf16.h>

#define NBLK 32
#define CAP  1024
#define DK   256
#define DV   256
#define HID  768
#define NQ   8192

#define NEG_INF (-__builtin_inff())

typedef __bf16 bfv8 __attribute__((ext_vector_type(8)));
typedef float  f32x4  __attribute__((ext_vector_type(4)));
typedef float  f32x16 __attribute__((ext_vector_type(16)));

__device__ __forceinline__ unsigned short f2bf(float x){
  unsigned int u = __float_as_uint(x);
  u += 0x7FFFu + ((u >> 16) & 1u);   // round-to-nearest-even
  return (unsigned short)(u >> 16);
}

// ------------- transpose + cast: src[z][R][C] f32 -> dst[z][C][R] bf16 -------------
__global__ void k_transpose_cast(const float* __restrict__ src, unsigned short* __restrict__ dst,
                                 int R, int C){
  __shared__ float tile[64][65];
  int r0 = blockIdx.x * 64, c0 = blockIdx.y * 64;
  size_t base = (size_t)blockIdx.z * (size_t)R * (size_t)C;
  int t = threadIdx.x;
  #pragma unroll
  for (int it = 0; it < 16; ++it){
    int idx = it * 256 + t;
    int ri = idx >> 6, ci = idx & 63;
    tile[ri][ci] = src[base + (size_t)(r0 + ri) * C + (c0 + ci)];
  }
  __syncthreads();
  #pragma unroll
  for (int it = 0; it < 16; ++it){
    int idx = it * 256 + t;
    int ci = idx >> 6, ri = idx & 63;
    dst[base + (size_t)(c0 + ci) * R + (r0 + ri)] = f2bf(tile[ri][ci]);
  }
}

// ------------- pack K into QK^T fragment order -------------
// Kp[(((b*32+t)*16+ks)*64 + l)*8 + j] = K[b][t*32 + (l&31)][ks*16 + (l>>5)*8 + j]
__global__ void k_packK(const float* __restrict__ MK, unsigned short* __restrict__ Kp){
  int id = blockIdx.x * 256 + threadIdx.x;          // (b,t,ks,l) : 32*32*16*64 = 1,048,576
  int l  = id & 63, ks = (id >> 6) & 15, tt = (id >> 10) & 31, b = id >> 15;
  int lq = l & 31, hi = l >> 5;
  const float* sp = MK + ((size_t)(b * CAP + tt * 32 + lq)) * DK + ks * 16 + hi * 8;
  float4 a0 = *reinterpret_cast<const float4*>(sp);
  float4 a1 = *reinterpret_cast<const float4*>(sp + 4);
  union { unsigned short s[8]; int4 v; } o;
  o.s[0]=f2bf(a0.x); o.s[1]=f2bf(a0.y); o.s[2]=f2bf(a0.z); o.s[3]=f2bf(a0.w);
  o.s[4]=f2bf(a1.x); o.s[5]=f2bf(a1.y); o.s[6]=f2bf(a1.z); o.s[7]=f2bf(a1.w);
  *reinterpret_cast<int4*>(Kp + (size_t)id * 8) = o.v;
}

// ------------- pack V into PV fragment order -------------
// Vp[((((b*32+t)*8+rt)*2+ks2)*64 + l)*8 + j] = V[b][t*32 + ks2*16 + (l>>5)*8 + j][rt*32 + (l&31)]
__global__ void k_packV(const float* __restrict__ MV, unsigned short* __restrict__ Vp){
  int id = blockIdx.x * 256 + threadIdx.x;          // (b,t,rt,ks2,l) : 32*32*8*2*64 = 1,048,576
  int l  = id & 63, ks2 = (id >> 6) & 1, rt = (id >> 7) & 7, tt = (id >> 10) & 31, b = id >> 15;
  int lq = l & 31, hi = l >> 5;
  int c0 = tt * 32 + ks2 * 16 + hi * 8;
  int dv = rt * 32 + lq;
  union { unsigned short s[8]; int4 v; } o;
  #pragma unroll
  for (int j = 0; j < 8; ++j)
    o.s[j] = f2bf(MV[((size_t)(b * CAP + c0 + j)) * DV + dv]);
  *reinterpret_cast<int4*>(Vp + (size_t)id * 8) = o.v;
}

// ------------- q-projection: one wave per 16 rows; writes PACKED fragment order -------------
__global__ __launch_bounds__(64)
void k_qproj3(const float* __restrict__ hs, const unsigned short* __restrict__ WkT,
              const float* __restrict__ bk, const float* __restrict__ lnw,
              const float* __restrict__ lnb, unsigned short* __restrict__ qp){
  int l = threadIdx.x, fr = l & 15, g = l >> 4;
  int r0 = blockIdx.x * 16;
  f32x4 acc[16];
  #pragma unroll
  for (int i = 0; i < 16; ++i) acc[i] = f32x4{0.f,0.f,0.f,0.f};
  for (int k0 = 0; k0 < HID; k0 += 32){
    const float* ap = hs + (size_t)(r0 + fr) * HID + k0 + g * 8;
    float4 a0 = *reinterpret_cast<const float4*>(ap);
    float4 a1 = *reinterpret_cast<const float4*>(ap + 4);
    union { unsigned short u[8]; bfv8 v; } A;
    A.u[0]=f2bf(a0.x); A.u[1]=f2bf(a0.y); A.u[2]=f2bf(a0.z); A.u[3]=f2bf(a0.w);
    A.u[4]=f2bf(a1.x); A.u[5]=f2bf(a1.y); A.u[6]=f2bf(a1.z); A.u[7]=f2bf(a1.w);
    #pragma unroll
    for (int dt = 0; dt < 16; ++dt){
      bfv8 b = *reinterpret_cast<const bfv8*>(WkT + (size_t)(dt*16 + fr) * HID + k0 + g*8);
      acc[dt] = __builtin_amdgcn_mfma_f32_16x16x32_bf16(A.v, b, acc[dt], 0, 0, 0);
    }
  }
  float sum[4] = {0,0,0,0}, sq[4] = {0,0,0,0};
  #pragma unroll
  for (int dt = 0; dt < 16; ++dt){
    float bkv = bk[dt*16 + fr];
    #pragma unroll
    for (int r = 0; r < 4; ++r){
      float v = acc[dt][r] + bkv;
      acc[dt][r] = v;
      sum[r] += v; sq[r] += v * v;
    }
  }
  #pragma unroll
  for (int r = 0; r < 4; ++r){
    float s = sum[r], q = sq[r];
    s += __shfl_xor(s, 1);  q += __shfl_xor(q, 1);
    s += __shfl_xor(s, 2);  q += __shfl_xor(q, 2);
    s += __shfl_xor(s, 4);  q += __shfl_xor(q, 4);
    s += __shfl_xor(s, 8);  q += __shfl_xor(q, 8);
    sum[r] = s; sq[r] = q;
  }
  #pragma unroll
  for (int dt = 0; dt < 16; ++dt){
    float w = lnw[dt*16 + fr], bb = lnb[dt*16 + fr];
    #pragma unroll
    for (int r = 0; r < 4; ++r){
      float mu  = sum[r] * (1.f/256.f);
      float var = sq[r] * (1.f/256.f) - mu * mu;
      float rsq = rsqrtf(var + 1e-5f);
      float v   = ((acc[dt][r] - mu) * rsq * w + bb) * 0.0625f;   // fold 1/sqrt(256)
      int qrow = r0 + 4*g + r;
      int d    = dt*16 + fr;
      int g0q = qrow >> 5, lqq = qrow & 31;
      int ksq = d >> 4, hiq = (d >> 3) & 1, jq = d & 7;
      qp[(((size_t)g0q*16 + ksq)*64 + hiq*32 + lqq)*8 + jq] = f2bf(v);
    }
  }
}

// ------------- flash attention: fragment-packed global operands, no K/V LDS, no barriers ----
__global__ __launch_bounds__(256, 2)
void k_attn4(const unsigned short* __restrict__ qp, const unsigned short* __restrict__ Kp,
             const unsigned short* __restrict__ Vp, const int* __restrict__ usage,
             float* __restrict__ retr){
  __shared__ unsigned short Pt[4][32*44];     // per-wave P [32 q][32 kv], stride 44 (2-way banks)
  const int t = threadIdx.x, w = t >> 6, l = t & 63;
  const int lq = l & 31, hi = l >> 5;
  const int bg = blockIdx.x, qt = blockIdx.y; // bg fastest -> XCD affinity per block-group
  const int g0 = qt * 4 + w;                  // 32-q group
  const int qrow = g0 * 32 + lq;

  // Q fragments (A/B 32x32x16 layout: row/col = lane&31, k = (lane>>5)*8 + e)
  bfv8 qf[16];
  #pragma unroll
  for (int ks = 0; ks < 16; ++ks)
    qf[ks] = *reinterpret_cast<const bfv8*>(qp + ((size_t)g0*16 + ks)*512 + l*8);

  unsigned short* Pw = &Pt[w][0];

  #pragma unroll 1
  for (int i = 0; i < 4; ++i){
    const int b = bg + i * 8;
    const int u = usage[b];
    const int nt = (u + 31) >> 5;
    float m = NEG_INF, lsum = 0.f;
    f32x16 O[8];
    #pragma unroll
    for (int r = 0; r < 8; ++r)
      #pragma unroll
      for (int j = 0; j < 16; ++j) O[r][j] = 0.f;

    #pragma unroll 1
    for (int tt = 0; tt < nt; ++tt){
      const int c0 = tt * 32;
      const unsigned short* Kt = Kp + ((size_t)(b*32 + tt) * 16) * 512;
      // ---- S^T = K * Q^T with two independent accumulation chains
      f32x16 s0, s1;
      #pragma unroll
      for (int j = 0; j < 16; ++j){ s0[j] = 0.f; s1[j] = 0.f; }
      #pragma unroll
      for (int ks = 0; ks < 8; ++ks){
        bfv8 k0 = *reinterpret_cast<const bfv8*>(Kt + (size_t)(2*ks)*512 + l*8);
        bfv8 k1 = *reinterpret_cast<const bfv8*>(Kt + (size_t)(2*ks+1)*512 + l*8);
        s0 = __builtin_amdgcn_mfma_f32_32x32x16_bf16(k0, qf[2*ks],   s0, 0, 0, 0);
        s1 = __builtin_amdgcn_mfma_f32_32x32x16_bf16(k1, qf[2*ks+1], s1, 0, 0, 0);
      }
      f32x16 s;
      #pragma unroll
      for (int j = 0; j < 16; ++j) s[j] = s0[j] + s1[j];
      // ---- mask + per-q max; S^T rows per reg: kv = (r&3)+8*(r>>2)+4*hi
      float tm = NEG_INF;
      #pragma unroll
      for (int r = 0; r < 16; ++r){
        int kv = (r & 3) + 8*(r >> 2) + 4*hi;
        if (c0 + kv >= u) s[r] = NEG_INF;
        tm = fmaxf(tm, s[r]);
      }
      tm = fmaxf(tm, __shfl_xor(tm, 32));
      float mn = fmaxf(m, tm);
      if (!__all(tm - m <= 8.f)){          // defer-max (T13)
        float sc = __expf(m - mn);
        m = mn; lsum *= sc;
        #pragma unroll
        for (int r = 0; r < 8; ++r) O[r] *= sc;
      }
      float rs = 0.f;
      #pragma unroll
      for (int r = 0; r < 16; ++r){
        float e = __expf(s[r] - m);
        s[r] = e; rs += e;
      }
      rs += __shfl_xor(rs, 32);
      lsum += rs;
      // ---- P -> per-wave LDS (row stride 44 shorts)
      #pragma unroll
      for (int blk = 0; blk < 4; ++blk){
        unsigned int w0 = (unsigned int)f2bf(s[4*blk])   | ((unsigned int)f2bf(s[4*blk+1]) << 16);
        unsigned int w1 = (unsigned int)f2bf(s[4*blk+2]) | ((unsigned int)f2bf(s[4*blk+3]) << 16);
        *reinterpret_cast<uint2*>(Pw + lq*44 + blk*8 + hi*4) = uint2{w0, w1};
      }
      asm volatile("s_waitcnt lgkmcnt(0)" ::: "memory");
      __builtin_amdgcn_sched_barrier(0);
      bfv8 pa0 = *reinterpret_cast<const bfv8*>(Pw + lq*44 + hi*8);
      bfv8 pa1 = *reinterpret_cast<const bfv8*>(Pw + lq*44 + 16 + hi*8);
      // ---- O^T += V^T * P : 8 independent chains
      const unsigned short* Vt = Vp + ((size_t)(b*32 + tt) * 16) * 512;
      __builtin_amdgcn_s_setprio(1);
      #pragma unroll
      for (int rt = 0; rt < 8; ++rt){
        bfv8 v0 = *reinterpret_cast<const bfv8*>(Vt + (size_t)(rt*2+0)*512 + l*8);
        bfv8 v1 = *reinterpret_cast<const bfv8*>(Vt + (size_t)(rt*2+1)*512 + l*8);
        O[rt] = __builtin_amdgcn_mfma_f32_32x32x16_bf16(v0, pa0, O[rt], 0, 0, 0);
        O[rt] = __builtin_amdgcn_mfma_f32_32x32x16_bf16(v1, pa1, O[rt], 0, 0, 0);
      }
      __builtin_amdgcn_s_setprio(0);
    }
    // ---- fold: dv = rt*32 + blk*8 + hi*4 + j, col q = lq
    float inv = 1.f / lsum;
    float* pb = retr + (size_t)qrow * DV;
    #pragma unroll
    for (int rt = 0; rt < 8; ++rt){
      #pragma unroll
      for (int blk = 0; blk < 4; ++blk){
        int dv0 = rt*32 + blk*8 + hi*4;
        #pragma unroll
        for (int j = 0; j < 4; ++j)
          atomicAdd(pb + dv0 + j, O[rt][blk*4 + j] * inv);
      }
    }
  }
}

// ------------- output projection: one wave per 16 rows x 256 cols -------------
__global__ __launch_bounds__(64)
void k_outproj3(const float* __restrict__ retr, const unsigned short* __restrict__ WoT,
                const float* __restrict__ bo, float* __restrict__ out){
  int l = threadIdx.x, fr = l & 15, g = l >> 4;
  int r0 = blockIdx.x * 16, c0 = blockIdx.y * 256;
  f32x4 acc[16];
  #pragma unroll
  for (int i = 0; i < 16; ++i) acc[i] = f32x4{0.f,0.f,0.f,0.f};
  #pragma unroll
  for (int k0 = 0; k0 < DV; k0 += 32){
    const float* ap = retr + (size_t)(r0 + fr) * DV + k0 + g*8;
    float4 a0 = *reinterpret_cast<const float4*>(ap);
    float4 a1 = *reinterpret_cast<const float4*>(ap + 4);
    union { unsigned short u[8]; bfv8 v; } A;
    A.u[0]=f2bf(a0.x); A.u[1]=f2bf(a0.y); A.u[2]=f2bf(a0.z); A.u[3]=f2bf(a0.w);
    A.u[4]=f2bf(a1.x); A.u[5]=f2bf(a1.y); A.u[6]=f2bf(a1.z); A.u[7]=f2bf(a1.w);
    #pragma unroll
    for (int dt = 0; dt < 16; ++dt){
      bfv8 b = *reinterpret_cast<const bfv8*>(WoT + (size_t)(c0 + dt*16 + fr) * DV + k0 + g*8);
      acc[dt] = __builtin_amdgcn_mfma_f32_16x16x32_bf16(A.v, b, acc[dt], 0, 0, 0);
    }
  }
  #pragma unroll
  for (int dt = 0; dt < 16; ++dt){
    float bv = bo[c0 + dt*16 + fr];
    #pragma unroll
    for (int r = 0; r < 4; ++r)
      out[(size_t)(r0 + 4*g + r) * HID + c0 + dt*16 + fr] = acc[dt][r] + bv;
  }
}

extern "C" void kernel_launch(void* const* d_in, const int* in_sizes, int n_in,
                              void* d_out, int out_size, void* d_ws, size_t ws_size,
                              hipStream_t stream){
  const float* hs  = (const float*)d_in[0];
  const float* Wk  = (const float*)d_in[1];
  const float* bk  = (const float*)d_in[2];
  const float* lnw = (const float*)d_in[3];
  const float* lnb = (const float*)d_in[4];
  const float* MK  = (const float*)d_in[5];
  const float* MV  = (const float*)d_in[6];
  const float* Wo  = (const float*)d_in[7];
  const float* bo  = (const float*)d_in[8];
  const int*   bu  = (const int*)d_in[9];
  float* out = (float*)d_out;

  char* ws = (char*)d_ws;
  unsigned short* qp   = (unsigned short*)(ws);                        //  4 MB  q packed bf16
  unsigned short* Kp   = (unsigned short*)(ws + (size_t)( 4u<<20));    // 16 MB  K packed bf16
  unsigned short* Vp   = (unsigned short*)(ws + (size_t)(20u<<20));    // 16 MB  V packed bf16
  unsigned short* WkT  = (unsigned short*)(ws + (size_t)(36u<<20));    // 384 KB [256][768]
  unsigned short* WoT  = (unsigned short*)(ws + (size_t)(36u<<20) + 393216); // 384 KB [768][256]
  float*          retr = (float*)(ws + (size_t)(37u<<20));             //  8 MB  retrieved f32
                                                                        // total 45 MB (proven safe)
  k_packK<<<dim3(4096), dim3(256), 0, stream>>>(MK, Kp);
  k_packV<<<dim3(4096), dim3(256), 0, stream>>>(MV, Vp);
  k_transpose_cast<<<dim3(12, 4, 1), dim3(256), 0, stream>>>(Wk, WkT, HID, DK);
  k_transpose_cast<<<dim3(4, 12, 1), dim3(256), 0, stream>>>(Wo, WoT, DV, HID);
  k_qproj3<<<dim3(512), dim3(64), 0, stream>>>(hs, WkT, bk, lnw, lnb, qp);
  hipMemsetAsync(retr, 0, (size_t)NQ * DV * sizeof(float), stream);
  k_attn4<<<dim3(8, 64), dim3(256), 0, stream>>>(qp, Kp, Vp, bu, retr);
  k_outproj3<<<dim3(512, 3), dim3(64), 0, stream>>>(retr, WoT, bo, out);
}